// Round 10
// baseline (731.252 us; speedup 1.0000x reference)
//
#include <hip/hip_runtime.h>
#include <stdint.h>

typedef unsigned short ushort_t;
typedef __attribute__((ext_vector_type(8))) short bf16x8;   // 8 bf16 in 4 VGPRs
typedef __attribute__((ext_vector_type(4))) float f32x4;

#define BKT_SHIFT 8
#define BKT_W     256
#define NB_MAX    512
#define KB_ITERS  16
#define KB_CHUNK  (256 * KB_ITERS)   // 4096 edges per block
#define PSLICES   64

// ---------------- helpers ----------------

__device__ __forceinline__ ushort_t f2bf(float f) {
    union { float f; uint32_t u; } a; a.f = f;
    uint32_t u = a.u;
    uint32_t r = (u + 0x7FFFu + ((u >> 16) & 1u)) >> 16;
    return (ushort_t)r;
}
__device__ __forceinline__ float bf_lo(uint32_t p) { return __uint_as_float(p << 16); }
__device__ __forceinline__ float bf_hi(uint32_t p) { return __uint_as_float(p & 0xFFFF0000u); }

// local exclusive scan of bhist[0..NB) into bb[0..512]; 256 threads.
__device__ __forceinline__ void local_bucket_scan(const int* __restrict__ bhist, int NB,
                                                  int* pr, int* bb) {
    int t = threadIdx.x;
    int h0 = (2 * t < NB) ? bhist[2 * t] : 0;
    int h1 = (2 * t + 1 < NB) ? bhist[2 * t + 1] : 0;
    pr[t] = h0 + h1;
    __syncthreads();
    for (int off = 1; off < 256; off <<= 1) {
        int x = (t >= off) ? pr[t - off] : 0;
        __syncthreads();
        pr[t] += x;
        __syncthreads();
    }
    int ex = pr[t] - (h0 + h1);
    bb[2 * t] = ex;
    bb[2 * t + 1] = ex + h0;
    __syncthreads();
}

// ---------------- kW_init: weight convert + zero small state ----------------
__global__ __launch_bounds__(256) void kW_init(const float* __restrict__ W1,
                                               const float* __restrict__ W2,
                                               ushort_t* __restrict__ Wt1,
                                               ushort_t* __restrict__ Wt2,
                                               int* __restrict__ bhist,
                                               int* __restrict__ bcnt,
                                               float* __restrict__ pooled,   // PSLICES*128
                                               int* __restrict__ counter) {
    int b = blockIdx.x, t = threadIdx.x;
    if (b < 64) {
        int i = b * 256 + t;
        int k = i >> 7, nn = i & 127;
        Wt1[nn * 128 + k] = f2bf(W1[i]);
        Wt2[nn * 128 + k] = f2bf(W2[i]);
    } else {
        for (int i = t; i < NB_MAX; i += 256) { bhist[i] = 0; bcnt[i] = 0; }
        for (int i = t; i < PSLICES * 128; i += 256) pooled[i] = 0.f;
        if (t == 0) *counter = 0;
    }
}

// ---------------- kA_hist ----------------
__global__ __launch_bounds__(256) void kA_hist(const int* __restrict__ dst, int E, int NB,
                                               int* __restrict__ bhist) {
    __shared__ int lh[NB_MAX];
    int t = threadIdx.x;
    for (int i = t; i < NB; i += 256) lh[i] = 0;
    __syncthreads();
    for (int e = blockIdx.x * 256 + t; e < E; e += gridDim.x * 256)
        atomicAdd(&lh[dst[e] >> BKT_SHIFT], 1);
    __syncthreads();
    for (int i = t; i < NB; i += 256)
        if (lh[i]) atomicAdd(&bhist[i], lh[i]);
}

// ---------------- kB_bucket ----------------
__global__ __launch_bounds__(256) void kB_bucket(const int* __restrict__ src,
                                                 const int* __restrict__ dst, int E, int NB,
                                                 const int* __restrict__ bhist,
                                                 int* __restrict__ bcnt,
                                                 uint32_t* __restrict__ bpack) {
    __shared__ int lh[NB_MAX];
    __shared__ int pr[256];
    __shared__ int bb[NB_MAX];
    int t = threadIdx.x;
    local_bucket_scan(bhist, NB, pr, bb);
    for (int i = t; i < NB; i += 256) lh[i] = 0;
    __syncthreads();

    int base = blockIdx.x * KB_CHUNK;
    int dreg[KB_ITERS], rank[KB_ITERS];
#pragma unroll
    for (int i = 0; i < KB_ITERS; i++) {
        int e = base + t + i * 256;
        if (e < E) {
            int d = dst[e];
            dreg[i] = d;
            rank[i] = atomicAdd(&lh[d >> BKT_SHIFT], 1);
        } else {
            dreg[i] = -1; rank[i] = 0;
        }
    }
    __syncthreads();
    for (int i = t; i < NB; i += 256) {
        int c = lh[i];
        lh[i] = c ? (bb[i] + atomicAdd(&bcnt[i], c)) : 0;
    }
    __syncthreads();
#pragma unroll
    for (int i = 0; i < KB_ITERS; i++) {
        int e = base + t + i * 256;
        if (dreg[i] >= 0) {
            int d = dreg[i];
            int pos = lh[d >> BKT_SHIFT] + rank[i];
            bpack[pos] = ((uint32_t)src[e] << 8) | (uint32_t)(d & (BKT_W - 1));
        }
    }
}

// ---------------- kC_build ----------------
__global__ __launch_bounds__(256) void kC_build(const uint32_t* __restrict__ bpack,
                                                const int* __restrict__ bhist, int NB, int n,
                                                float* __restrict__ dinv,
                                                int* __restrict__ offs,
                                                int* __restrict__ csr) {
    __shared__ int pr[256];
    __shared__ int bb[NB_MAX];
    __shared__ int cnt[BKT_W];
    __shared__ int s[BKT_W];
    __shared__ int cur[BKT_W];
    int t = threadIdx.x;
    int b = blockIdx.x;
    local_bucket_scan(bhist, NB, pr, bb);
    int nb0 = b << BKT_SHIFT;
    int wlen = min(BKT_W, n - nb0);
    int e0 = bb[b], e1 = bb[b + 1];

    cnt[t] = 0;
    __syncthreads();
    for (int e = e0 + t; e < e1; e += 256)
        atomicAdd(&cnt[bpack[e] & (BKT_W - 1)], 1);
    __syncthreads();

    int v = cnt[t];
    s[t] = v;
    __syncthreads();
    for (int off = 1; off < 256; off <<= 1) {
        int x = (t >= off) ? s[t - off] : 0;
        __syncthreads();
        s[t] += x;
        __syncthreads();
    }
    int myoff = e0 + s[t] - v;
    cur[t] = myoff;
    if (t < wlen) {
        offs[nb0 + t] = myoff;
        dinv[nb0 + t] = rsqrtf((float)(v + 1));
    }
    if (b == NB - 1 && t == 0) offs[n] = e1;
    __syncthreads();

    for (int e = e0 + t; e < e1; e += 256) {
        uint32_t p = bpack[e];
        int pos = atomicAdd(&cur[p & (BKT_W - 1)], 1);
        csr[pos] = (int)(p >> 8);
    }
}

// ---------------- MFMA GEMM (unchanged) ----------------
template <bool AF32>
__global__ __launch_bounds__(256) void k_gemm_mfma(const void* __restrict__ Av,
                                                   const ushort_t* __restrict__ Wt,
                                                   const float* __restrict__ dinv,
                                                   ushort_t* __restrict__ C, int n) {
    __shared__ ushort_t al[64 * 136];
    __shared__ ushort_t wl[128 * 136];
    const int t = threadIdx.x;
    const int l = t & 63;
    const int wave = t >> 6;
    const int lane15 = l & 15;
    const int quad = l >> 4;
    const int m0 = blockIdx.x * 64;
    const int rows = min(64, n - m0);

#pragma unroll
    for (int i = 0; i < 8; i++) {
        int f = t + 256 * i;
        int r = f >> 4, c = f & 15;
        *(uint4*)(&wl[r * 136 + c * 8]) = ((const uint4*)Wt)[f];
    }
    if (AF32) {
        const float4* Ap = (const float4*)((const float*)Av + (size_t)m0 * 128);
        int nf = rows * 32;
#pragma unroll
        for (int i = 0; i < 8; i++) {
            int f = t + 256 * i;
            float4 v = make_float4(0.f, 0.f, 0.f, 0.f);
            if (f < nf) v = Ap[f];
            ushort4 us;
            us.x = f2bf(v.x); us.y = f2bf(v.y); us.z = f2bf(v.z); us.w = f2bf(v.w);
            int r = f >> 5, c = f & 31;
            *(ushort4*)(&al[r * 136 + c * 4]) = us;
        }
    } else {
        const uint4* Ap = (const uint4*)((const ushort_t*)Av + (size_t)m0 * 128);
        int nf = rows * 16;
#pragma unroll
        for (int i = 0; i < 4; i++) {
            int f = t + 256 * i;
            uint4 v = make_uint4(0, 0, 0, 0);
            if (f < nf) v = Ap[f];
            int r = f >> 4, c = f & 15;
            *(uint4*)(&al[r * 136 + c * 8]) = v;
        }
    }
    __syncthreads();

    f32x4 acc[8];
#pragma unroll
    for (int nt = 0; nt < 8; nt++) acc[nt] = (f32x4){0.f, 0.f, 0.f, 0.f};

    const int arow = wave * 16 + lane15;
#pragma unroll
    for (int kt = 0; kt < 4; kt++) {
        bf16x8 af = *(const bf16x8*)(&al[arow * 136 + kt * 32 + quad * 8]);
#pragma unroll
        for (int nt = 0; nt < 8; nt++) {
            bf16x8 bfr = *(const bf16x8*)(&wl[(nt * 16 + lane15) * 136 + kt * 32 + quad * 8]);
            acc[nt] = __builtin_amdgcn_mfma_f32_16x16x32_bf16(af, bfr, acc[nt], 0, 0, 0);
        }
    }

    const int rbase = m0 + wave * 16 + quad * 4;
    float dsc[4];
#pragma unroll
    for (int r = 0; r < 4; r++)
        dsc[r] = (rbase + r < n) ? dinv[rbase + r] : 0.f;
#pragma unroll
    for (int nt = 0; nt < 8; nt++)
#pragma unroll
        for (int r = 0; r < 4; r++) {
            int row = rbase + r;
            if (row < n) C[(size_t)row * 128 + nt * 16 + lane15] = f2bf(acc[nt][r] * dsc[r]);
        }
}

// ---------------- Aggregation: 4-rows-per-VMEM-instruction gather ----------------
// Wave = 4 groups x 16 lanes. Group g loads row u as dwordx4 (16B/lane = 256B row).
// Lane (g,j) accumulates channels j*8..j*8+7. Butterfly xor(16,32) combines groups.
// POOL: layer-2 variant — no h store; relu'd rows accumulate into pooled slices,
// completion counter, last block does the FC into out[128].
template <bool POOL>
__global__ __launch_bounds__(256) void k_agg4(const ushort_t* __restrict__ xw,
                                              const int* __restrict__ offs,
                                              const int* __restrict__ csr,
                                              const float* __restrict__ dinv,
                                              const float* __restrict__ bias,
                                              ushort_t* __restrict__ out,
                                              float* __restrict__ pooled,
                                              int* __restrict__ counter,
                                              const float* __restrict__ Wfc,
                                              const float* __restrict__ bfc,
                                              float* __restrict__ fco,
                                              float invN, int n) {
    __shared__ float red[4 * 128];
    __shared__ float pl[128];
    __shared__ int lastFlag;
    const int t = threadIdx.x;
    const int l = t & 63;
    const int g = l >> 4;
    const int j = l & 15;
    const int wv = (blockIdx.x << 2) | (t >> 6);
    const int ws = gridDim.x << 2;
    const uint4* xw4 = (const uint4*)xw;

    const float4 b0 = ((const float4*)bias)[j * 2];
    const float4 b1 = ((const float4*)bias)[j * 2 + 1];
    float ps[8] = {0.f, 0.f, 0.f, 0.f, 0.f, 0.f, 0.f, 0.f};

    for (int v = wv; v < n; v += ws) {
        int e0 = __builtin_amdgcn_readfirstlane(offs[v]);
        int e1 = __builtin_amdgcn_readfirstlane(offs[v + 1]);
        int cnt = e1 - e0 + 1;   // entry 0 = self loop
        float a[8] = {0.f, 0.f, 0.f, 0.f, 0.f, 0.f, 0.f, 0.f};

        for (int page = 0; page < cnt; page += 64) {
            // lane l holds index of entry (page + l): coalesced csr load
            int ii_l = page + l;
            int u_l = v;
            if (ii_l > 0 && ii_l < cnt) u_l = csr[e0 + ii_l - 1];
            int plen = min(64, cnt - page);
            for (int base = 0; base < plen; base += 16) {
                uint4 p[4];
#pragma unroll
                for (int q = 0; q < 4; q++) {
                    int ii = base + q * 4 + g;
                    int u = __shfl(u_l, ii, 64);
                    uint4 val = make_uint4(0, 0, 0, 0);
                    if (ii < plen) val = xw4[(size_t)u * 16 + j];
                    p[q] = val;
                }
#pragma unroll
                for (int q = 0; q < 4; q++) {
                    a[0] += bf_lo(p[q].x); a[1] += bf_hi(p[q].x);
                    a[2] += bf_lo(p[q].y); a[3] += bf_hi(p[q].y);
                    a[4] += bf_lo(p[q].z); a[5] += bf_hi(p[q].z);
                    a[6] += bf_lo(p[q].w); a[7] += bf_hi(p[q].w);
                }
            }
        }
        // combine the 4 groups
#pragma unroll
        for (int k = 0; k < 8; k++) {
            a[k] += __shfl_xor(a[k], 16, 64);
            a[k] += __shfl_xor(a[k], 32, 64);
        }
        float dv = dinv[v];
        float o[8];
        o[0] = fmaxf(fmaf(a[0], dv, b0.x), 0.f);
        o[1] = fmaxf(fmaf(a[1], dv, b0.y), 0.f);
        o[2] = fmaxf(fmaf(a[2], dv, b0.z), 0.f);
        o[3] = fmaxf(fmaf(a[3], dv, b0.w), 0.f);
        o[4] = fmaxf(fmaf(a[4], dv, b1.x), 0.f);
        o[5] = fmaxf(fmaf(a[5], dv, b1.y), 0.f);
        o[6] = fmaxf(fmaf(a[6], dv, b1.z), 0.f);
        o[7] = fmaxf(fmaf(a[7], dv, b1.w), 0.f);
        if (!POOL) {
            if (g == 0) {
                uint4 st;
                st.x = ((uint32_t)f2bf(o[1]) << 16) | (uint32_t)f2bf(o[0]);
                st.y = ((uint32_t)f2bf(o[3]) << 16) | (uint32_t)f2bf(o[2]);
                st.z = ((uint32_t)f2bf(o[5]) << 16) | (uint32_t)f2bf(o[4]);
                st.w = ((uint32_t)f2bf(o[7]) << 16) | (uint32_t)f2bf(o[6]);
                ((uint4*)out)[(size_t)v * 16 + j] = st;
            }
        } else {
            if (g == 0) {
#pragma unroll
                for (int k = 0; k < 8; k++) ps[k] += o[k];
            }
        }
    }

    if (POOL) {
        const int w = t >> 6;
        if (g == 0) {
#pragma unroll
            for (int k = 0; k < 8; k++) red[w * 128 + j * 8 + k] = ps[k];
        }
        __syncthreads();
        if (t < 128) {
            float s = red[t] + red[128 + t] + red[256 + t] + red[384 + t];
            atomicAdd(&pooled[(blockIdx.x & (PSLICES - 1)) * 128 + t], s);
        }
        __threadfence();
        __syncthreads();
        if (t == 0) {
            int old = atomicAdd(counter, 1);
            lastFlag = (old == (int)gridDim.x - 1);
        }
        __syncthreads();
        if (lastFlag) {
            if (t < 128) {
                float acc = 0.f;
                for (int s = 0; s < PSLICES; s++)
                    acc += atomicAdd(&pooled[s * 128 + t], 0.f);   // coherent read
                pl[t] = acc;
            }
            __syncthreads();
            if (t < 128) {
                float acc = bfc[t];
#pragma unroll 8
                for (int k = 0; k < 128; k++)
                    acc = fmaf(pl[k] * invN, Wfc[k * 128 + t], acc);
                fco[t] = acc;
            }
        }
    }
}

// ---------------- launcher ----------------
extern "C" void kernel_launch(void* const* d_in, const int* in_sizes, int n_in,
                              void* d_out, int out_size, void* d_ws, size_t ws_size,
                              hipStream_t stream) {
    const float* x    = (const float*)d_in[0];
    const int*   ei   = (const int*)d_in[1];
    const float* W1   = (const float*)d_in[2];
    const float* b1   = (const float*)d_in[3];
    const float* W2   = (const float*)d_in[4];
    const float* b2   = (const float*)d_in[5];
    const float* Wfc  = (const float*)d_in[6];
    const float* bfc  = (const float*)d_in[7];
    float*       out  = (float*)d_out;

    const int n = in_sizes[0] / 128;
    const int E = in_sizes[1] / 2;
    const int* src = ei;
    const int* dst = ei + E;
    const int NB = (n + BKT_W - 1) >> BKT_SHIFT;   // 391

    char* w = (char*)d_ws;
    ushort_t* xw = (ushort_t*)w; w += (size_t)n * 128 * sizeof(ushort_t);
    ushort_t* h  = (ushort_t*)w; w += (size_t)n * 128 * sizeof(ushort_t);
    int*      csr   = (int*)w;      w += (size_t)E * sizeof(int);
    uint32_t* bpack = (uint32_t*)w; w += (size_t)E * sizeof(uint32_t);
    float* dinv = (float*)w;  w += (size_t)n * sizeof(float);
    int*   offs = (int*)w;    w += (size_t)(n + 1) * sizeof(int);
    w = (char*)(((uintptr_t)w + 127) & ~(uintptr_t)127);
    int*   bhist = (int*)w;   w += NB_MAX * sizeof(int);
    int*   bcnt  = (int*)w;   w += NB_MAX * sizeof(int);
    int*   counter = (int*)w; w += 32 * sizeof(int);
    float* pooled = (float*)w; w += PSLICES * 128 * sizeof(float);
    ushort_t* Wt1 = (ushort_t*)w; w += 16384 * sizeof(ushort_t);
    ushort_t* Wt2 = (ushort_t*)w; w += 16384 * sizeof(ushort_t);

    const int ntiles64 = (n + 63) / 64;
    const float invN = 1.0f / (float)n;

    kW_init<<<65, 256, 0, stream>>>(W1, W2, Wt1, Wt2, bhist, bcnt, pooled, counter);
    kA_hist<<<1024, 256, 0, stream>>>(dst, E, NB, bhist);
    kB_bucket<<<(E + KB_CHUNK - 1) / KB_CHUNK, 256, 0, stream>>>(src, dst, E, NB, bhist, bcnt, bpack);
    kC_build<<<NB, 256, 0, stream>>>(bpack, bhist, NB, n, dinv, offs, csr);

    k_gemm_mfma<true><<<ntiles64, 256, 0, stream>>>(x, Wt1, dinv, xw, n);
    k_agg4<false><<<8192, 256, 0, stream>>>(xw, offs, csr, dinv, b1, h,
                                            pooled, counter, Wfc, bfc, out, invN, n);
    k_gemm_mfma<false><<<ntiles64, 256, 0, stream>>>(h, Wt2, dinv, xw, n);
    k_agg4<true><<<4096, 256, 0, stream>>>(xw, offs, csr, dinv, b2, h,
                                           pooled, counter, Wfc, bfc, out, invN, n);
}